// Round 14
// baseline (189.340 us; speedup 1.0000x reference)
//
#include <hip/hip_runtime.h>
#include <hip/hip_bf16.h>

#define HH 9
#define WW 9
#define HW 81
#define CC 16
#define DD 34
#define SS 6561
#define NHEAD 2
#define HD 17
#define FF 2048
#define EPSF 1e-5f

#define NTILES 52
#define NSPLIT2 26
#define QB 64

#define NIP 7168
#define NOP 3072
#define NW1 131072
#define NW2 98304
#define NLTOT (NIP + NOP + NW1 + NW2)
#define LPREP_BLOCKS 1872
#define NKF 425984
#define NVF 212992
#define NV16 13312
#define ZERO_WORDS 332800
#define ZERO_BLOCKS 1300

#define NEAB 124416
#define NVFL1 12288
#define KSPLIT 8     // fl2 FF K-splits
#define KS1 2        // fl1 FF K-splits (8 kt each)

typedef __attribute__((ext_vector_type(8))) short bf16x8;
typedef __attribute__((ext_vector_type(4))) float f32x4;

__device__ __forceinline__ unsigned short f2b(float f) {
  unsigned int u = __float_as_uint(f);
  u += 0x7fffu + ((u >> 16) & 1u);
  return (unsigned short)(u >> 16);
}

// ---- dispatch 1: block 0 = conv; 1..1872 = weight pack; rest zero kfp/vfp/v16 ----
__global__ __launch_bounds__(256) void prep_kernel(
    const float* __restrict__ obs, const float* __restrict__ w1, const float* __restrict__ b1,
    const float* __restrict__ w2, const float* __restrict__ b2,
    float* __restrict__ cell, int* __restrict__ aidx,
    const float* __restrict__ ipw, const float* __restrict__ opw,
    const float* __restrict__ l1w, const float* __restrict__ l2w,
    unsigned short* __restrict__ ipwp, unsigned short* __restrict__ opwp,
    unsigned short* __restrict__ w1p, unsigned short* __restrict__ w2p,
    unsigned short* __restrict__ kfp, unsigned short* __restrict__ vfp,
    float* __restrict__ v16) {
  int bx = blockIdx.x;
  int t = threadIdx.x;
  if (bx == 0) {
    __shared__ float s_obs[2][11][11];
    __shared__ float s_w1[288];
    __shared__ float s_w2[2304];
    __shared__ float s_b1[16], s_b2[16];
    __shared__ float y1[CC][121];
    for (int i = t; i < 2 * 121; i += 256) ((float*)s_obs)[i] = 0.f;
    for (int i = t; i < CC * 121; i += 256) ((float*)y1)[i] = 0.f;
    for (int i = t; i < 288; i += 256) s_w1[i] = w1[i];
    for (int i = t; i < 2304; i += 256) s_w2[i] = w2[i];
    if (t < 16) { s_b1[t] = b1[t]; s_b2[t] = b2[t]; }
    __syncthreads();
    for (int i = t; i < 2 * HW; i += 256) {
      int ic = i / HW, p = i % HW;
      s_obs[ic][1 + p / WW][1 + p % WW] = obs[i];
    }
    __syncthreads();
    if (t == 0) {
      int best = 0; float bv = s_obs[0][1][1];
      for (int p = 1; p < HW; p++) {
        float v = s_obs[0][1 + p / WW][1 + p % WW];
        if (v > bv) { bv = v; best = p; }
      }
      *aidx = best;
    }
    for (int idx = t; idx < CC * HW; idx += 256) {
      int c = idx / HW, p = idx % HW;
      int i = p / WW, j = p % WW;
      float acc = s_b1[c];
#pragma unroll
      for (int ic = 0; ic < 2; ic++)
#pragma unroll
        for (int di = 0; di < 3; di++)
#pragma unroll
          for (int dj = 0; dj < 3; dj++)
            acc += s_obs[ic][i + di][j + dj] * s_w1[((c * 2 + ic) * 3 + di) * 3 + dj];
      y1[c][(i + 1) * 11 + (j + 1)] = fmaxf(acc, 0.f);
    }
    __syncthreads();
    for (int idx = t; idx < CC * HW; idx += 256) {
      int c = idx / HW, p = idx % HW;
      int i = p / WW, j = p % WW;
      float acc = s_b2[c];
#pragma unroll
      for (int ic = 0; ic < CC; ic++)
#pragma unroll
        for (int di = 0; di < 3; di++)
#pragma unroll
          for (int dj = 0; dj < 3; dj++)
            acc += y1[ic][(i + di) * 11 + (j + dj)] * s_w2[((c * CC + ic) * 3 + di) * 3 + dj];
      cell[p * CC + c] = fmaxf(acc, 0.f);
    }
  } else if (bx <= LPREP_BLOCKS) {
    int i = (bx - 1) * 256 + t;
    int layer = i / NLTOT;
    int r = i % NLTOT;
    if (r < NIP) {
      int n = r >> 6, k = r & 63;
      ipwp[layer * NIP + r] =
          (n < 102 && k < DD) ? f2b(ipw[(size_t)layer * 102 * DD + n * DD + k]) : (unsigned short)0;
    } else if (r < NIP + NOP) {
      int rr = r - NIP;
      int n = rr >> 6, k = rr & 63;
      opwp[layer * NOP + rr] =
          (n < DD && k < DD) ? f2b(opw[(size_t)layer * DD * DD + n * DD + k]) : (unsigned short)0;
    } else if (r < NIP + NOP + NW1) {
      int rr = r - NIP - NOP;
      int f = rr >> 6, k = rr & 63;
      w1p[layer * NW1 + rr] =
          (k < DD) ? f2b(l1w[(size_t)layer * FF * DD + f * DD + k]) : (unsigned short)0;
    } else {
      int rr = r - NIP - NOP - NW1;
      int d = rr >> 11, kk = rr & 2047;
      w2p[layer * NW2 + rr] =
          (d < DD) ? f2b(l2w[(size_t)layer * DD * FF + d * FF + kk]) : (unsigned short)0;
    }
  } else {
    int zi = (bx - 1 - LPREP_BLOCKS) * 256 + t;
    if (zi < NKF / 2) ((unsigned int*)kfp)[zi] = 0u;
    else if (zi < NKF / 2 + NVF / 2) ((unsigned int*)vfp)[zi - NKF / 2] = 0u;
    else if (zi < ZERO_WORDS) v16[zi - NKF / 2 - NVF / 2] = 0.f;
  }
}

// ---- dispatch 2: layer-1 separable qkv tables ----
__global__ __launch_bounds__(256) void ptprep_kernel(
    const float* __restrict__ cell, const float* __restrict__ ipw,
    const float* __restrict__ ipb, float* __restrict__ Pt) {
  int idx = blockIdx.x * 256 + threadIdx.x;
  if (idx >= 2 * HW * 102) return;
  int part = idx / (HW * 102);
  int rem = idx % (HW * 102);
  int a = rem / 102, n = rem % 102;
  float ra = (float)(a / WW) * 0.25f, ca = (float)(a % WW) * 0.25f;
  float acc;
  if (part == 0) {
    acc = ipb[n] + ipw[n * DD + 32] * ra + ipw[n * DD + 33] * ca;
    for (int f = 0; f < CC; f++) acc += ipw[n * DD + f] * cell[a * CC + f];
  } else {
    acc = -(ipw[n * DD + 32] * ra + ipw[n * DD + 33] * ca);
    for (int f = 0; f < CC; f++) acc += ipw[n * DD + CC + f] * cell[a * CC + f];
  }
  Pt[idx] = acc;
}

// ---- dispatch 3: exp-factorized score matrices + L1 V fragment table ----
__global__ __launch_bounds__(256) void expprep_kernel(
    const float* __restrict__ Pt, float* __restrict__ eAB,
    unsigned short* __restrict__ vfragL1) {
  int idx = blockIdx.x * 256 + threadIdx.x;
  const float scale = 0.24253562503633297f;
  if (idx < NEAB) {
    int a = idx % 96; int rest = idx / 96;
    int row = rest % 81; rest /= 81;
    int ab = rest & 1, p = (rest >> 1) & 1, h = rest >> 2;
    float e = 0.f;
    if (a < HW) {
      const float* qrow = Pt + (size_t)ab * (HW * 102) + row * 102 + h * HD;
      const float* krow = Pt + (size_t)p * (HW * 102) + a * 102 + DD + h * HD;
      float dot = 0.f;
#pragma unroll
      for (int d = 0; d < HD; d++) dot += qrow[d] * krow[d];
      e = __expf(fminf(dot * scale, 40.f));
    }
    eAB[idx] = e;
  } else if (idx < NEAB + NVFL1) {
    int j = idx - NEAB;
    int a = j % 96; int rest = j / 96;
    int n = rest % 32; rest /= 32;
    int p = rest & 1, h = rest >> 1;
    float v = 0.f;
    if (a < HW) {
      if (n < HD) v = Pt[(size_t)p * (HW * 102) + a * 102 + 2 * DD + h * HD + n];
      else if (n == HD) v = 1.f;
    }
    vfragL1[((size_t)(h * 2 + p) * 32 + n) * 96 + a] = f2b(v);
  }
}

// ---- dispatch 4: fl1a: tokens + E-product attention + proj + LN1 + PARTIAL FF ----
// grid (411, KS1). Redundant prologue per K-split; 8 kt tiles per block.
// sp==0 writes LN1 output to xlnL1 (fp32, full S).
__global__ __launch_bounds__(256) void fl1a_kernel(
    const float* __restrict__ cell, const float* __restrict__ eAB,
    const unsigned short* __restrict__ vfragL1,
    const unsigned short* __restrict__ opwp, const float* __restrict__ opb,
    const float* __restrict__ g1v, const float* __restrict__ b1v,
    const unsigned short* __restrict__ w1p, const unsigned short* __restrict__ w2p,
    const float* __restrict__ fb1,
    float* __restrict__ xlnL1, float* __restrict__ ypart1) {
  __shared__ __align__(16) unsigned short sE[4][16 * 96];
  __shared__ __align__(16) unsigned short soA[16 * 72];
  __shared__ float sxF[16][35];
  __shared__ __align__(16) unsigned short sxA2[16 * 72];
  __shared__ __align__(16) unsigned short hw_[4][16 * 40];
  __shared__ float yred[4][16][49];
  int t = threadIdx.x;
  int w = t >> 6, lane = t & 63, quad = lane >> 4, col = lane & 15;
  int sp = blockIdx.y;
  int r0 = blockIdx.x * 16;
  int nr = min(16, SS - r0);

  for (int i = t; i < 16 * 72; i += 256) { soA[i] = 0; sxA2[i] = 0; }
  for (int i = t; i < 16 * 35; i += 256) ((float*)sxF)[i] = 0.f;
  for (int i = t; i < nr * DD; i += 256) {
    int r = i / DD, d = i - r * DD;
    int row = r0 + r;
    int ii = row / HW, jj = row - ii * HW;
    float v;
    if (d < CC) v = cell[ii * CC + d];
    else if (d < 2 * CC) v = cell[jj * CC + (d - CC)];
    else if (d == 32) v = (float)((ii / WW) - (jj / WW)) * 0.25f;
    else v = (float)((ii % WW) - (jj % WW)) * 0.25f;
    sxF[r][d] = v;
  }

  {
    int h = w >> 1, p = w & 1;
    const float* eA = eAB + ((size_t)((h * 2 + p) * 2 + 0) * 81) * 96;
    const float* eB = eAB + ((size_t)((h * 2 + p) * 2 + 1) * 81) * 96;
    int tl = lane >> 2, asub = lane & 3;
    int row = r0 + tl;
    int tc = row < SS ? row : SS - 1;
    int it = tc / HW, jt = tc - it * HW;
    const float* eAr = eA + it * 96 + asub * 24;
    const float* eBr = eB + jt * 96 + asub * 24;
    unsigned short etmp[24];
#pragma unroll
    for (int k = 0; k < 24; k++) etmp[k] = f2b(eAr[k] * eBr[k]);
    unsigned short* Eb = &sE[w][tl * 96 + asub * 24];
#pragma unroll
    for (int k = 0; k < 3; k++)
      *(bf16x8*)(Eb + k * 8) = *(bf16x8*)(etmp + k * 8);
    const unsigned short* vf = vfragL1 + (size_t)(h * 2 + p) * 32 * 96;
    f32x4 acc0 = {0.f, 0.f, 0.f, 0.f}, acc1 = {0.f, 0.f, 0.f, 0.f};
#pragma unroll
    for (int c = 0; c < 3; c++) {
      bf16x8 ea = *(const bf16x8*)&sE[w][col * 96 + c * 32 + quad * 8];
      bf16x8 vb0 = *(const bf16x8*)&vf[col * 96 + c * 32 + quad * 8];
      bf16x8 vb1 = *(const bf16x8*)&vf[(16 + col) * 96 + c * 32 + quad * 8];
      acc0 = __builtin_amdgcn_mfma_f32_16x16x32_bf16(ea, vb0, acc0, 0, 0, 0);
      acc1 = __builtin_amdgcn_mfma_f32_16x16x32_bf16(ea, vb1, acc1, 0, 0, 0);
    }
    float Sr[4];
#pragma unroll
    for (int r = 0; r < 4; r++) Sr[r] = __shfl(acc1[r], (lane & 48) + 1);
#pragma unroll
    for (int r = 0; r < 4; r++) {
      int rr = quad * 4 + r;
      float inv = 1.f / Sr[r];
      yred[w][rr][col] = acc0[r] * inv;
      if (col == 0) yred[w][rr][16] = acc1[r] * inv;
    }
  }
  __syncthreads();
  for (int i = t; i < 16 * DD; i += 256) {
    int r = i / DD, dd = i - r * DD;
    int h2 = dd / HD, d2 = dd - h2 * HD;
    soA[r * 72 + dd] = f2b(yred[2 * h2][r][d2] + yred[2 * h2 + 1][r][d2]);
  }
  __syncthreads();

  if (w == 0) {
    bf16x8 a0 = *(const bf16x8*)&soA[col * 72 + quad * 8];
    bf16x8 a1 = *(const bf16x8*)&soA[col * 72 + 32 + quad * 8];
    f32x4 y[3];
#pragma unroll
    for (int nt = 0; nt < 3; nt++) {
      int n = nt * 16 + col;
      bf16x8 b0 = *(const bf16x8*)&opwp[n * 64 + quad * 8];
      bf16x8 b1 = *(const bf16x8*)&opwp[n * 64 + 32 + quad * 8];
      f32x4 acc = {0.f, 0.f, 0.f, 0.f};
      acc = __builtin_amdgcn_mfma_f32_16x16x32_bf16(a0, b0, acc, 0, 0, 0);
      y[nt] = __builtin_amdgcn_mfma_f32_16x16x32_bf16(a1, b1, acc, 0, 0, 0);
    }
    float yv[3][4];
    float s1[4] = {0.f, 0.f, 0.f, 0.f}, s2[4] = {0.f, 0.f, 0.f, 0.f};
#pragma unroll
    for (int nt = 0; nt < 3; nt++) {
      int d = nt * 16 + col;
      bool vd = d < DD;
      float ob = vd ? opb[d] : 0.f;
#pragma unroll
      for (int r = 0; r < 4; r++) {
        int row = quad * 4 + r;
        float v = vd ? (y[nt][r] + ob + sxF[row][d]) : 0.f;
        yv[nt][r] = v;
        s1[r] += v;
        s2[r] += v * v;
      }
    }
#pragma unroll
    for (int msk = 1; msk <= 8; msk <<= 1)
#pragma unroll
      for (int r = 0; r < 4; r++) {
        s1[r] += __shfl_xor(s1[r], msk);
        s2[r] += __shfl_xor(s2[r], msk);
      }
#pragma unroll
    for (int r = 0; r < 4; r++) {
      int row = quad * 4 + r;
      float mean = s1[r] * (1.f / DD);
      float var = s2[r] * (1.f / DD) - mean * mean;
      float rs = rsqrtf(var + EPSF);
#pragma unroll
      for (int nt = 0; nt < 3; nt++) {
        int d = nt * 16 + col;
        if (d < DD) {
          float o = (yv[nt][r] - mean) * rs * g1v[d] + b1v[d];
          sxA2[row * 72 + d] = f2b(o);
          if (sp == 0 && row < nr)
            xlnL1[(size_t)(r0 + row) * DD + d] = o;
        }
      }
    }
  }
  __syncthreads();

  // partial FF: 8 kt tiles
  bf16x8 a0 = *(const bf16x8*)&sxA2[col * 72 + quad * 8];
  bf16x8 a1 = *(const bf16x8*)&sxA2[col * 72 + 32 + quad * 8];
  unsigned short* myh = &hw_[w][0];
  f32x4 acc3[3];
#pragma unroll
  for (int nt = 0; nt < 3; nt++) acc3[nt] = (f32x4){0.f, 0.f, 0.f, 0.f};
  for (int kt2 = 0; kt2 < 8; kt2++) {
    int kt = sp * 8 + kt2;
    int fbase = kt * 128 + w * 32;
#pragma unroll
    for (int nt = 0; nt < 2; nt++) {
      int f = fbase + nt * 16 + col;
      bf16x8 b0f = *(const bf16x8*)&w1p[f * 64 + quad * 8];
      bf16x8 b1f = *(const bf16x8*)&w1p[f * 64 + 32 + quad * 8];
      f32x4 hacc = {0.f, 0.f, 0.f, 0.f};
      hacc = __builtin_amdgcn_mfma_f32_16x16x32_bf16(a0, b0f, hacc, 0, 0, 0);
      hacc = __builtin_amdgcn_mfma_f32_16x16x32_bf16(a1, b1f, hacc, 0, 0, 0);
      float bias = fb1[f];
#pragma unroll
      for (int r = 0; r < 4; r++) {
        float hv = fmaxf(hacc[r] + bias, 0.f);
        myh[(quad * 4 + r) * 40 + nt * 16 + col] = f2b(hv);
      }
    }
    bf16x8 pa = *(const bf16x8*)&myh[col * 40 + quad * 8];
#pragma unroll
    for (int nt = 0; nt < 3; nt++) {
      int n = nt * 16 + col;
      bf16x8 wb = *(const bf16x8*)&w2p[(size_t)n * FF + fbase + quad * 8];
      acc3[nt] = __builtin_amdgcn_mfma_f32_16x16x32_bf16(pa, wb, acc3[nt], 0, 0, 0);
    }
  }
#pragma unroll
  for (int nt = 0; nt < 3; nt++)
#pragma unroll
    for (int r = 0; r < 4; r++)
      yred[w][quad * 4 + r][nt * 16 + col] = acc3[nt][r];
  __syncthreads();
  if (w == 0) {
    for (int i = lane; i < nr * DD; i += 64) {
      int r = i / DD, d = i - r * DD;
      float v = yred[0][r][d] + yred[1][r][d] + yred[2][r][d] + yred[3][r][d];
      ypart1[((size_t)sp * SS + r0 + r) * DD + d] = v;
    }
  }
}

// ---- dispatch 5: fl1b: reduce KS1 partials + bias + residual + LN2 -> x ----
__global__ __launch_bounds__(256) void fl1b_kernel(
    const float* __restrict__ ypart1, const float* __restrict__ xlnL1,
    const float* __restrict__ fb2, const float* __restrict__ g2v,
    const float* __restrict__ b2v, float* __restrict__ x) {
  int t = threadIdx.x;
  int row = blockIdx.x * 32 + (t >> 3);
  int s8 = t & 7;
  if (row >= SS) return;
  float yv[5];
  float s1 = 0.f, s2 = 0.f;
  int cnt = 0;
  for (int d = s8; d < DD; d += 8) {
    float v = fb2[d] + xlnL1[(size_t)row * DD + d];
#pragma unroll
    for (int sp = 0; sp < KS1; sp++)
      v += ypart1[((size_t)sp * SS + row) * DD + d];
    yv[cnt++] = v;
    s1 += v;
    s2 += v * v;
  }
  s1 += __shfl_xor(s1, 1); s2 += __shfl_xor(s2, 1);
  s1 += __shfl_xor(s1, 2); s2 += __shfl_xor(s2, 2);
  s1 += __shfl_xor(s1, 4); s2 += __shfl_xor(s2, 4);
  float mean = s1 * (1.f / DD);
  float var = s2 * (1.f / DD) - mean * mean;
  float rs = rsqrtf(var + EPSF);
  cnt = 0;
  for (int d = s8; d < DD; d += 8)
    x[(size_t)row * DD + d] = (yv[cnt++] - mean) * rs * g2v[d] + b2v[d];
}

// ---- dispatch 6: layer-2 qkv, 16 rows/block. Blocks 0..410: K/V fragment scatter;
//      blocks 411..418: Q for 128 rows at runtime base -> qkv. ----
__global__ __launch_bounds__(256) void qkv2_kernel(
    const float* __restrict__ x, const unsigned short* __restrict__ ipwp,
    const float* __restrict__ ipb, const int* __restrict__ abase,
    float* __restrict__ qkv, unsigned short* __restrict__ kfp,
    unsigned short* __restrict__ vfp, float* __restrict__ v16) {
  __shared__ __align__(16) unsigned short sxA[16 * 72];
  int t = threadIdx.x;
  int w = t >> 6, lane = t & 63, quad = lane >> 4, col = lane & 15;
  bool qpart = blockIdx.x >= 411;
  int row0 = qpart ? (abase[0] * HW + (blockIdx.x - 411) * 16) : blockIdx.x * 16;
  int nr = min(16, SS - row0);
  for (int i = t; i < 16 * 72; i += 256) sxA[i] = 0;
  __syncthreads();
  for (int i = t; i < nr * DD; i += 256) {
    int r = i / DD, d = i - r * DD;
    sxA[r * 72 + d] = f2b(x[(size_t)(row0 + r) * DD + d]);
  }
  __syncthreads();
  bf16x8 a0 = *(const bf16x8*)&sxA[col * 72 + quad * 8];
  bf16x8 a1 = *(const bf16x8*)&sxA[col * 72 + 32 + quad * 8];
  if (!qpart) {
    int npass = (w == 0) ? 2 : 1;
    for (int pass = 0; pass < npass; pass++) {
      int nt = (pass == 0) ? w : 4;
      int n = DD + nt * 16 + col;       // 34..113
      int nc = n < 112 ? n : 111;
      bf16x8 b0 = *(const bf16x8*)&ipwp[nc * 64 + quad * 8];
      bf16x8 b1 = *(const bf16x8*)&ipwp[nc * 64 + 32 + quad * 8];
      f32x4 acc = {0.f, 0.f, 0.f, 0.f};
      acc = __builtin_amdgcn_mfma_f32_16x16x32_bf16(a0, b0, acc, 0, 0, 0);
      acc = __builtin_amdgcn_mfma_f32_16x16x32_bf16(a1, b1, acc, 0, 0, 0);
      if (n < 102) {
        float bias = ipb[n];
        int kd = n - DD;
#pragma unroll
        for (int r = 0; r < 4; r++) {
          int m = quad * 4 + r;
          if (m >= nr) continue;
          int tok = row0 + m;
          float val = acc[r] + bias;
          int T = tok >> 7, tl = tok & 127;
          if (kd < 2 * HD) {
            int h = kd >= HD;
            int d = kd - h * HD;
            int colf = tl >> 3, ntk = tl & 7;
            kfp[(((size_t)h * NTILES + T) * 8 + ntk) * 512 +
                ((d >> 3) * 16 + colf) * 8 + (d & 7)] = f2b(val);
          } else {
            int vd = kd - 2 * HD;
            int h = vd >= HD;
            int d = vd - h * HD;
            if (d < 16) {
              int c = tl >> 5, qf = (tl >> 3) & 3, j = tl & 7;
              vfp[(((size_t)h * NTILES + T) * 4 + c) * 512 +
                  (qf * 16 + d) * 8 + j] = f2b(val);
            } else {
              v16[(size_t)h * (NTILES * 128) + tok] = val;
            }
          }
        }
      }
    }
  } else {
    if (w < 3) {
      int n = w * 16 + col;             // 0..47
      bf16x8 b0 = *(const bf16x8*)&ipwp[n * 64 + quad * 8];
      bf16x8 b1 = *(const bf16x8*)&ipwp[n * 64 + 32 + quad * 8];
      f32x4 acc = {0.f, 0.f, 0.f, 0.f};
      acc = __builtin_amdgcn_mfma_f32_16x16x32_bf16(a0, b0, acc, 0, 0, 0);
      acc = __builtin_amdgcn_mfma_f32_16x16x32_bf16(a1, b1, acc, 0, 0, 0);
      if (n < DD) {
        float bias = ipb[n];
#pragma unroll
        for (int r = 0; r < 4; r++) {
          int m = row0 + quad * 4 + r;
          if (m < SS) qkv[(size_t)m * 102 + n] = acc[r] + bias;
        }
      }
    }
  }
}

// ---- dispatch 7: layer-2 attention ----
__global__ __launch_bounds__(256) void attn2_kernel(
    const float* __restrict__ qkv, const unsigned short* __restrict__ kfp,
    const unsigned short* __restrict__ vfp, const float* __restrict__ v16,
    const int* __restrict__ abase,
    float* __restrict__ opart, float* __restrict__ lpart) {
  __shared__ __align__(16) unsigned short scb[4][16 * 136];
  int t = threadIdx.x, w = t >> 6, lane = t & 63, quad = lane >> 4, col = lane & 15;
  int h = blockIdx.y, sp = blockIdx.z;
  int base = abase[0] * HW;
  int q0 = blockIdx.x * QB;
  const float scale = 0.24253562503633297f;
  const unsigned short* kf = kfp + (size_t)h * (NTILES * 8 * 512);
  const unsigned short* vf = vfp + (size_t)h * (NTILES * 4 * 512);
  const float* v16h = v16 + (size_t)h * (NTILES * 128);
  unsigned short* myscb = &scb[w][0];

  int mq = base + q0 + w * 16 + col;
  int qc = mq < SS ? mq : SS - 1;
  bf16x8 aq;
#pragma unroll
  for (int j = 0; j < 8; j++) {
    int d = quad * 8 + j;
    aq[j] = (short)((d < HD) ? f2b(qkv[(size_t)qc * 102 + h * HD + d] * scale) : 0);
  }

  f32x4 oacc = {0.f, 0.f, 0.f, 0.f};
  float o16a[4] = {0.f, 0.f, 0.f, 0.f};
  float lreg[4] = {0.f, 0.f, 0.f, 0.f};

  for (int tile = sp; tile < NTILES; tile += NSPLIT2) {
    int k0 = tile * 128;
    const unsigned short* kt = kf + (size_t)tile * (8 * 512);
    f32x4 s[8];
#pragma unroll
    for (int nt = 0; nt < 8; nt++) {
      bf16x8 kb = *(const bf16x8*)(kt + nt * 512 + lane * 8);
      f32x4 z = {0.f, 0.f, 0.f, 0.f};
      s[nt] = __builtin_amdgcn_mfma_f32_16x16x32_bf16(aq, kb, z, 0, 0, 0);
    }
    if (k0 + 128 > SS) {
#pragma unroll
      for (int nt = 0; nt < 8; nt++)
        if (k0 + col * 8 + nt >= SS) {
          s[nt][0] = -1e30f; s[nt][1] = -1e30f; s[nt][2] = -1e30f; s[nt][3] = -1e30f;
        }
    }
#pragma unroll
    for (int r = 0; r < 4; r++) {
      bf16x8 pv;
      float psl = 0.f;
#pragma unroll
      for (int nt = 0; nt < 8; nt++) {
        float p = __expf(fminf(s[nt][r], 70.f));
        s[nt][r] = p;
        psl += p;
        pv[nt] = (short)f2b(p);
      }
      lreg[r] += psl;
      *(bf16x8*)(myscb + (quad * 4 + r) * 136 + col * 8) = pv;
    }
    f32x4 va = *(const f32x4*)(v16h + k0 + col * 8);
    f32x4 vb4 = *(const f32x4*)(v16h + k0 + col * 8 + 4);
#pragma unroll
    for (int r = 0; r < 4; r++) {
      o16a[r] += s[0][r] * va[0] + s[1][r] * va[1] + s[2][r] * va[2] + s[3][r] * va[3]
               + s[4][r] * vb4[0] + s[5][r] * vb4[1] + s[6][r] * vb4[2] + s[7][r] * vb4[3];
    }
    const unsigned short* vt = vf + (size_t)tile * (4 * 512);
#pragma unroll
    for (int c = 0; c < 4; c++) {
      bf16x8 pa = *(const bf16x8*)(myscb + col * 136 + c * 32 + quad * 8);
      bf16x8 vbf = *(const bf16x8*)(vt + c * 512 + lane * 8);
      oacc = __builtin_amdgcn_mfma_f32_16x16x32_bf16(pa, vbf, oacc, 0, 0, 0);
    }
  }
#pragma unroll
  for (int msk = 1; msk <= 8; msk <<= 1)
#pragma unroll
    for (int r = 0; r < 4; r++) {
      o16a[r] += __shfl_xor(o16a[r], msk);
      lreg[r] += __shfl_xor(lreg[r], msk);
    }
  size_t obase = ((size_t)sp * NHEAD + h) * 128;
#pragma unroll
  for (int r = 0; r < 4; r++) {
    int ql = q0 + w * 16 + quad * 4 + r;
    if (ql < HW) {
      opart[(obase + ql) * HD + col] = oacc[r];
      if (col == 0) {
        opart[(obase + ql) * HD + 16] = o16a[r];
        lpart[obase + ql] = lreg[r];
      }
    }
  }
}

// ---- dispatch 8: fl2a: combine + proj + LN1 + partial FF ----
__global__ __launch_bounds__(256) void fl2a_kernel(
    const float* __restrict__ opart, const float* __restrict__ lpart,
    const unsigned short* __restrict__ opwp, const float* __restrict__ opb,
    const float* __restrict__ g1v, const float* __restrict__ b1v,
    const unsigned short* __restrict__ w1p, const unsigned short* __restrict__ w2p,
    const float* __restrict__ fb1, const int* __restrict__ abase,
    const float* __restrict__ x, float* __restrict__ xln, float* __restrict__ ypart) {
  __shared__ __align__(16) unsigned short soA[16 * 72];
  __shared__ float sxF[16][35];
  __shared__ __align__(16) unsigned short sxA2[16 * 72];
  __shared__ __align__(16) unsigned short hw_[4][16 * 40];
  __shared__ float yred[4][16][49];
  int t = threadIdx.x;
  int w = t >> 6, lane = t & 63, quad = lane >> 4, col = lane & 15;
  int sp = blockIdx.y;
  int base = abase[0] * HW;
  int ql0 = blockIdx.x * 16;
  int nr = min(16, HW - ql0);
  int r0 = base + ql0;

  for (int i = t; i < 16 * 72; i += 256) { soA[i] = 0; sxA2[i] = 0; }
  for (int i = t; i < 16 * 35; i += 256) ((float*)sxF)[i] = 0.f;
  __syncthreads();
  for (int i = t; i < nr * DD; i += 256) {
    int r = i / DD, rem = i - r * DD;
    sxF[r][rem] = x[(size_t)(r0 + r) * DD + rem];
    int ql = ql0 + r;
    int h = rem / HD, d = rem - h * HD;
    float L = 0.f, O = 0.f;
#pragma unroll
    for (int s = 0; s < NSPLIT2; s++) {
      L += lpart[((size_t)s * NHEAD + h) * 128 + ql];
      O += opart[(((size_t)s * NHEAD + h) * 128 + ql) * HD + d];
    }
    soA[r * 72 + rem] = f2b(O / L);
  }
  __syncthreads();
  if (w == 0) {
    bf16x8 a0 = *(const bf16x8*)&soA[col * 72 + quad * 8];
    bf16x8 a1 = *(const bf16x8*)&soA[col * 72 + 32 + quad * 8];
    f32x4 y[3];
#pragma unroll
    for (int nt = 0; nt < 3; nt++) {
      int n = nt * 16 + col;
      bf16x8 b0 = *(const bf16x8*)&opwp[n * 64 + quad * 8];
      bf16x8 b1 = *(const bf16x8*)&opwp[n * 64 + 32 + quad * 8];
      f32x4 acc = {0.f, 0.f, 0.f, 0.f};
      acc = __builtin_amdgcn_mfma_f32_16x16x32_bf16(a0, b0, acc, 0, 0, 0);
      y[nt] = __builtin_amdgcn_mfma_f32_16x16x32_bf16(a1, b1, acc, 0, 0, 0);
    }
    float yv[3][4];
    float s1[4] = {0.f, 0.f, 0.f, 0.f}, s2[4] = {0.f, 0.f, 0.f, 0.f};
#pragma unroll
    for (int nt = 0; nt < 3; nt++) {
      int d = nt * 16 + col;
      bool vd = d < DD;
      float ob = vd ? opb[d] : 0.f;
#pragma unroll
      for (int r = 0; r < 4; r++) {
        int row = quad * 4 + r;
        float v = vd ? (y[nt][r] + ob + sxF[row][d]) : 0.f;
        yv[nt][r] = v;
        s1[r] += v;
        s2[r] += v * v;
      }
    }
#pragma unroll
    for (int msk = 1; msk <= 8; msk <<= 1)
#pragma unroll
      for (int r = 0; r < 4; r++) {
        s1[r] += __shfl_xor(s1[r], msk);
        s2[r] += __shfl_xor(s2[r], msk);
      }
#pragma unroll
    for (int r = 0; r < 4; r++) {
      int row = quad * 4 + r;
      float mean = s1[r] * (1.f / DD);
      float var = s2[r] * (1.f / DD) - mean * mean;
      float rs = rsqrtf(var + EPSF);
#pragma unroll
      for (int nt = 0; nt < 3; nt++) {
        int d = nt * 16 + col;
        if (d < DD) {
          float o = (yv[nt][r] - mean) * rs * g1v[d] + b1v[d];
          sxA2[row * 72 + d] = f2b(o);
          if (sp == 0 && row < nr)
            xln[(size_t)(ql0 + row) * DD + d] = o;
        }
      }
    }
  }
  __syncthreads();
  bf16x8 a0 = *(const bf16x8*)&sxA2[col * 72 + quad * 8];
  bf16x8 a1 = *(const bf16x8*)&sxA2[col * 72 + 32 + quad * 8];
  unsigned short* myh = &hw_[w][0];
  f32x4 acc3[3];
#pragma unroll
  for (int nt = 0; nt < 3; nt++) acc3[nt] = (f32x4){0.f, 0.f, 0.f, 0.f};
  for (int kt2 = 0; kt2 < 2; kt2++) {
    int kt = sp * 2 + kt2;
    int fbase = kt * 128 + w * 32;
#pragma unroll
    for (int nt = 0; nt < 2; nt++) {
      int f = fbase + nt * 16 + col;
      bf16x8 b0f = *(const bf16x8*)&w1p[f * 64 + quad * 8];
      bf16x8 b1f = *(const bf16x8*)&w1p[f * 64 + 32 + quad * 8];
      f32x4 hacc = {0.f, 0.f, 0.f, 0.f};
      hacc = __builtin_amdgcn_mfma_f32_16x16x32_bf16(a0, b0f, hacc, 0, 0, 0);
      hacc = __builtin_amdgcn_mfma_f32_16x16x32_bf16(a1, b1f, hacc, 0, 0, 0);
      float bias = fb1[f];
#pragma unroll
      for (int r = 0; r < 4; r++) {
        float hv = fmaxf(hacc[r] + bias, 0.f);
        myh[(quad * 4 + r) * 40 + nt * 16 + col] = f2b(hv);
      }
    }
    bf16x8 pa = *(const bf16x8*)&myh[col * 40 + quad * 8];
#pragma unroll
    for (int nt = 0; nt < 3; nt++) {
      int n = nt * 16 + col;
      bf16x8 wb = *(const bf16x8*)&w2p[(size_t)n * FF + fbase + quad * 8];
      acc3[nt] = __builtin_amdgcn_mfma_f32_16x16x32_bf16(pa, wb, acc3[nt], 0, 0, 0);
    }
  }
#pragma unroll
  for (int nt = 0; nt < 3; nt++)
#pragma unroll
    for (int r = 0; r < 4; r++)
      yred[w][quad * 4 + r][nt * 16 + col] = acc3[nt][r];
  __syncthreads();
  if (w == 0) {
    for (int i = lane; i < nr * DD; i += 64) {
      int r = i / DD, d = i - r * DD;
      float v = yred[0][r][d] + yred[1][r][d] + yred[2][r][d] + yred[3][r][d];
      ypart[((size_t)sp * HW + ql0 + r) * DD + d] = v;
    }
  }
}

// ---- dispatch 9: fl2b ----
__global__ __launch_bounds__(256) void fl2b_kernel(
    const float* __restrict__ ypart, const float* __restrict__ xln,
    const float* __restrict__ fb2, const float* __restrict__ g2v,
    const float* __restrict__ b2v, const int* __restrict__ abase,
    float* __restrict__ x) {
  int t = threadIdx.x;
  int row = blockIdx.x * 32 + (t >> 3);
  int s8 = t & 7;
  if (row >= HW) return;
  int base = abase[0] * HW;
  float yv[5];
  float s1 = 0.f, s2 = 0.f;
  int cnt = 0;
  for (int d = s8; d < DD; d += 8) {
    float v = fb2[d] + xln[(size_t)row * DD + d];
#pragma unroll
    for (int sp = 0; sp < KSPLIT; sp++)
      v += ypart[((size_t)sp * HW + row) * DD + d];
    yv[cnt++] = v;
    s1 += v;
    s2 += v * v;
  }
  s1 += __shfl_xor(s1, 1); s2 += __shfl_xor(s2, 1);
  s1 += __shfl_xor(s1, 2); s2 += __shfl_xor(s2, 2);
  s1 += __shfl_xor(s1, 4); s2 += __shfl_xor(s2, 4);
  float mean = s1 * (1.f / DD);
  float var = s2 * (1.f / DD) - mean * mean;
  float rs = rsqrtf(var + EPSF);
  cnt = 0;
  for (int d = s8; d < DD; d += 8)
    x[(size_t)(base + row) * DD + d] = (yv[cnt++] - mean) * rs * g2v[d] + b2v[d];
}

// ---- dispatch 10: final ----
__global__ __launch_bounds__(64) void final_kernel(
    const float* __restrict__ x, const int* __restrict__ aidx, float* __restrict__ out) {
  int d = threadIdx.x;
  if (d >= DD) return;
  int start = (*aidx) * HW;
  float acc = 0.f;
  for (int j = 0; j < HW; j++) acc += x[(size_t)(start + j) * DD + d];
  out[d] = acc * (1.f / HW);
}

extern "C" void kernel_launch(void* const* d_in, const int* in_sizes, int n_in,
                              void* d_out, int out_size, void* d_ws, size_t ws_size,
                              hipStream_t stream) {
  const float* obs = (const float*)d_in[0];
  const float* c1w = (const float*)d_in[1];
  const float* c1b = (const float*)d_in[2];
  const float* c2w = (const float*)d_in[3];
  const float* c2b = (const float*)d_in[4];
  const float* ipw = (const float*)d_in[5];
  const float* ipb = (const float*)d_in[6];
  const float* opw = (const float*)d_in[7];
  const float* opb = (const float*)d_in[8];
  const float* l1w = (const float*)d_in[9];
  const float* l1b = (const float*)d_in[10];
  const float* l2w = (const float*)d_in[11];
  const float* l2b = (const float*)d_in[12];
  const float* g1 = (const float*)d_in[13];
  const float* b1 = (const float*)d_in[14];
  const float* g2 = (const float*)d_in[15];
  const float* b2 = (const float*)d_in[16];
  float* out = (float*)d_out;

  float* ws = (float*)d_ws;
  size_t off = 0;
  float* x     = ws + off; off += SS * DD;
  float* qkv   = ws + off; off += SS * 102;
  float* cell  = ws + off; off += HW * CC;
  int*   aidx  = (int*)(ws + off); off += 1;
  off = (off + 3) & ~(size_t)3;
  float* Pt    = ws + off; off += 2 * HW * 102;
  float* opart = ws + off; off += (size_t)NSPLIT2 * NHEAD * 128 * HD;
  float* lpart = ws + off; off += (size_t)NSPLIT2 * NHEAD * 128;
  float* eAB   = ws + off; off += NEAB;
  float* xlnL1 = ws + off; off += SS * DD;
  float* ypart1 = ws + off; off += (size_t)KS1 * SS * DD;
  float* xln   = ws + off; off += HW * DD;
  float* ypart = ws + off; off += (size_t)KSPLIT * HW * DD;
  off = (off + 3) & ~(size_t)3;
  unsigned short* vfragL1 = (unsigned short*)(ws + off); off += NVFL1 / 2;
  unsigned short* kfp  = (unsigned short*)(ws + off); off += NKF / 2;
  unsigned short* vfp  = (unsigned short*)(ws + off); off += NVF / 2;
  float* v16 = ws + off; off += NV16;
  unsigned short* ipwp = (unsigned short*)(ws + off); off += 2 * NIP / 2;
  unsigned short* opwp = (unsigned short*)(ws + off); off += 2 * NOP / 2;
  unsigned short* w1p  = (unsigned short*)(ws + off); off += 2 * NW1 / 2;
  unsigned short* w2p  = (unsigned short*)(ws + off); off += 2 * NW2 / 2;

  const int prep_grid = 1 + LPREP_BLOCKS + ZERO_BLOCKS;
  const int pt_blocks = (2 * HW * 102 + 255) / 256;
  const int exp_blocks = (NEAB + NVFL1 + 255) / 256;
  const int fl1_blocks = (SS + 15) / 16;   // 411
  const int red_blocks = (SS + 31) / 32;   // 206

  prep_kernel<<<prep_grid, 256, 0, stream>>>(
      obs, c1w, c1b, c2w, c2b, cell, aidx,
      ipw, opw, l1w, l2w, ipwp, opwp, w1p, w2p, kfp, vfp, v16);
  ptprep_kernel<<<pt_blocks, 256, 0, stream>>>(cell, ipw, ipb, Pt);
  expprep_kernel<<<exp_blocks, 256, 0, stream>>>(Pt, eAB, vfragL1);
  dim3 f1g(fl1_blocks, KS1);
  fl1a_kernel<<<f1g, 256, 0, stream>>>(
      cell, eAB, vfragL1, opwp, opb, g1, b1, w1p, w2p, l1b, xlnL1, ypart1);
  fl1b_kernel<<<red_blocks, 256, 0, stream>>>(
      ypart1, xlnL1, l2b, g2, b2, x);
  qkv2_kernel<<<419, 256, 0, stream>>>(
      x, ipwp + NIP, ipb + 102, aidx, qkv, kfp, vfp, v16);
  dim3 a2g(2, NHEAD, NSPLIT2);
  attn2_kernel<<<a2g, 256, 0, stream>>>(qkv, kfp, vfp, v16, aidx, opart, lpart);
  dim3 f2g(6, KSPLIT);
  fl2a_kernel<<<f2g, 256, 0, stream>>>(
      opart, lpart, opwp + NOP, opb + DD, g1 + DD, b1 + DD,
      w1p + NW1, w2p + NW2, l1b + FF, aidx, x, xln, ypart);
  fl2b_kernel<<<3, 256, 0, stream>>>(
      ypart, xln, l2b + DD, g2 + DD, b2 + DD, aidx, x);
  final_kernel<<<1, 64, 0, stream>>>(x, aidx, out);
}

// Round 15
// 180.188 us; speedup vs baseline: 1.0508x; 1.0508x over previous
//
#include <hip/hip_runtime.h>
#include <hip/hip_bf16.h>

#define HH 9
#define WW 9
#define HW 81
#define CC 16
#define DD 34
#define SS 6561
#define NHEAD 2
#define HD 17
#define FF 2048
#define EPSF 1e-5f

#define NTILES 52
#define QB 64

#define NIP 7168
#define NOP 3072
#define NW1 131072
#define NW2 98304
#define NLTOT (NIP + NOP + NW1 + NW2)
#define LPREP_BLOCKS 1872
#define NKF 425984
#define NVF 212992
#define NV16 13312
#define NOSUM 4608                     // o_sum 128*34 + l_sum 2*128
#define ZERO_WORDS 337408              // NKF/2 + NVF/2 + NV16 + NOSUM
#define ZERO_BLOCKS 1318

#define NEAB 124416
#define NVFL1 12288
#define KSPLIT 16                      // fl2 FF K-splits (1 kt each)

typedef __attribute__((ext_vector_type(8))) short bf16x8;
typedef __attribute__((ext_vector_type(4))) float f32x4;

__device__ __forceinline__ unsigned short f2b(float f) {
  unsigned int u = __float_as_uint(f);
  u += 0x7fffu + ((u >> 16) & 1u);
  return (unsigned short)(u >> 16);
}

// ---- dispatch 1: block 0 = conv; 1..1872 = weight pack; rest zero kfp/vfp/v16/o_sum ----
__global__ __launch_bounds__(256) void prep_kernel(
    const float* __restrict__ obs, const float* __restrict__ w1, const float* __restrict__ b1,
    const float* __restrict__ w2, const float* __restrict__ b2,
    float* __restrict__ cell, int* __restrict__ aidx,
    const float* __restrict__ ipw, const float* __restrict__ opw,
    const float* __restrict__ l1w, const float* __restrict__ l2w,
    unsigned short* __restrict__ ipwp, unsigned short* __restrict__ opwp,
    unsigned short* __restrict__ w1p, unsigned short* __restrict__ w2p,
    unsigned short* __restrict__ kfp, unsigned short* __restrict__ vfp,
    float* __restrict__ v16, float* __restrict__ osum) {
  int bx = blockIdx.x;
  int t = threadIdx.x;
  if (bx == 0) {
    __shared__ float s_obs[2][11][11];
    __shared__ float s_w1[288];
    __shared__ float s_w2[2304];
    __shared__ float s_b1[16], s_b2[16];
    __shared__ float y1[CC][121];
    for (int i = t; i < 2 * 121; i += 256) ((float*)s_obs)[i] = 0.f;
    for (int i = t; i < CC * 121; i += 256) ((float*)y1)[i] = 0.f;
    for (int i = t; i < 288; i += 256) s_w1[i] = w1[i];
    for (int i = t; i < 2304; i += 256) s_w2[i] = w2[i];
    if (t < 16) { s_b1[t] = b1[t]; s_b2[t] = b2[t]; }
    __syncthreads();
    for (int i = t; i < 2 * HW; i += 256) {
      int ic = i / HW, p = i % HW;
      s_obs[ic][1 + p / WW][1 + p % WW] = obs[i];
    }
    __syncthreads();
    if (t == 0) {
      int best = 0; float bv = s_obs[0][1][1];
      for (int p = 1; p < HW; p++) {
        float v = s_obs[0][1 + p / WW][1 + p % WW];
        if (v > bv) { bv = v; best = p; }
      }
      *aidx = best;
    }
    for (int idx = t; idx < CC * HW; idx += 256) {
      int c = idx / HW, p = idx % HW;
      int i = p / WW, j = p % WW;
      float acc = s_b1[c];
#pragma unroll
      for (int ic = 0; ic < 2; ic++)
#pragma unroll
        for (int di = 0; di < 3; di++)
#pragma unroll
          for (int dj = 0; dj < 3; dj++)
            acc += s_obs[ic][i + di][j + dj] * s_w1[((c * 2 + ic) * 3 + di) * 3 + dj];
      y1[c][(i + 1) * 11 + (j + 1)] = fmaxf(acc, 0.f);
    }
    __syncthreads();
    for (int idx = t; idx < CC * HW; idx += 256) {
      int c = idx / HW, p = idx % HW;
      int i = p / WW, j = p % WW;
      float acc = s_b2[c];
#pragma unroll
      for (int ic = 0; ic < CC; ic++)
#pragma unroll
        for (int di = 0; di < 3; di++)
#pragma unroll
          for (int dj = 0; dj < 3; dj++)
            acc += y1[ic][(i + di) * 11 + (j + dj)] * s_w2[((c * CC + ic) * 3 + di) * 3 + dj];
      cell[p * CC + c] = fmaxf(acc, 0.f);
    }
  } else if (bx <= LPREP_BLOCKS) {
    int i = (bx - 1) * 256 + t;
    int layer = i / NLTOT;
    int r = i % NLTOT;
    if (r < NIP) {
      int n = r >> 6, k = r & 63;
      ipwp[layer * NIP + r] =
          (n < 102 && k < DD) ? f2b(ipw[(size_t)layer * 102 * DD + n * DD + k]) : (unsigned short)0;
    } else if (r < NIP + NOP) {
      int rr = r - NIP;
      int n = rr >> 6, k = rr & 63;
      opwp[layer * NOP + rr] =
          (n < DD && k < DD) ? f2b(opw[(size_t)layer * DD * DD + n * DD + k]) : (unsigned short)0;
    } else if (r < NIP + NOP + NW1) {
      int rr = r - NIP - NOP;
      int f = rr >> 6, k = rr & 63;
      w1p[layer * NW1 + rr] =
          (k < DD) ? f2b(l1w[(size_t)layer * FF * DD + f * DD + k]) : (unsigned short)0;
    } else {
      int rr = r - NIP - NOP - NW1;
      int d = rr >> 11, kk = rr & 2047;
      w2p[layer * NW2 + rr] =
          (d < DD) ? f2b(l2w[(size_t)layer * DD * FF + d * FF + kk]) : (unsigned short)0;
    }
  } else {
    int zi = (bx - 1 - LPREP_BLOCKS) * 256 + t;
    if (zi < NKF / 2) ((unsigned int*)kfp)[zi] = 0u;
    else if (zi < NKF / 2 + NVF / 2) ((unsigned int*)vfp)[zi - NKF / 2] = 0u;
    else if (zi < NKF / 2 + NVF / 2 + NV16) v16[zi - NKF / 2 - NVF / 2] = 0.f;
    else if (zi < ZERO_WORDS) osum[zi - NKF / 2 - NVF / 2 - NV16] = 0.f;
  }
}

// ---- dispatch 2: layer-1 separable qkv tables ----
__global__ __launch_bounds__(256) void ptprep_kernel(
    const float* __restrict__ cell, const float* __restrict__ ipw,
    const float* __restrict__ ipb, float* __restrict__ Pt) {
  int idx = blockIdx.x * 256 + threadIdx.x;
  if (idx >= 2 * HW * 102) return;
  int part = idx / (HW * 102);
  int rem = idx % (HW * 102);
  int a = rem / 102, n = rem % 102;
  float ra = (float)(a / WW) * 0.25f, ca = (float)(a % WW) * 0.25f;
  float acc;
  if (part == 0) {
    acc = ipb[n] + ipw[n * DD + 32] * ra + ipw[n * DD + 33] * ca;
    for (int f = 0; f < CC; f++) acc += ipw[n * DD + f] * cell[a * CC + f];
  } else {
    acc = -(ipw[n * DD + 32] * ra + ipw[n * DD + 33] * ca);
    for (int f = 0; f < CC; f++) acc += ipw[n * DD + CC + f] * cell[a * CC + f];
  }
  Pt[idx] = acc;
}

// ---- dispatch 3: exp-factorized score matrices + L1 V fragment table ----
__global__ __launch_bounds__(256) void expprep_kernel(
    const float* __restrict__ Pt, float* __restrict__ eAB,
    unsigned short* __restrict__ vfragL1) {
  int idx = blockIdx.x * 256 + threadIdx.x;
  const float scale = 0.24253562503633297f;
  if (idx < NEAB) {
    int a = idx % 96; int rest = idx / 96;
    int row = rest % 81; rest /= 81;
    int ab = rest & 1, p = (rest >> 1) & 1, h = rest >> 2;
    float e = 0.f;
    if (a < HW) {
      const float* qrow = Pt + (size_t)ab * (HW * 102) + row * 102 + h * HD;
      const float* krow = Pt + (size_t)p * (HW * 102) + a * 102 + DD + h * HD;
      float dot = 0.f;
#pragma unroll
      for (int d = 0; d < HD; d++) dot += qrow[d] * krow[d];
      e = __expf(fminf(dot * scale, 40.f));
    }
    eAB[idx] = e;
  } else if (idx < NEAB + NVFL1) {
    int j = idx - NEAB;
    int a = j % 96; int rest = j / 96;
    int n = rest % 32; rest /= 32;
    int p = rest & 1, h = rest >> 1;
    float v = 0.f;
    if (a < HW) {
      if (n < HD) v = Pt[(size_t)p * (HW * 102) + a * 102 + 2 * DD + h * HD + n];
      else if (n == HD) v = 1.f;
    }
    vfragL1[((size_t)(h * 2 + p) * 32 + n) * 96 + a] = f2b(v);
  }
}

// ---- dispatch 4: fused layer-1 (R12 structure) ----
__global__ __launch_bounds__(256) void fl1_kernel(
    const float* __restrict__ cell, const float* __restrict__ eAB,
    const unsigned short* __restrict__ vfragL1,
    const unsigned short* __restrict__ opwp, const float* __restrict__ opb,
    const float* __restrict__ g1v, const float* __restrict__ b1v,
    const unsigned short* __restrict__ w1p, const unsigned short* __restrict__ w2p,
    const float* __restrict__ fb1, const float* __restrict__ fb2,
    const float* __restrict__ g2v, const float* __restrict__ b2v,
    float* __restrict__ x) {
  __shared__ __align__(16) unsigned short sE[4][16 * 96];
  __shared__ __align__(16) unsigned short soA[16 * 72];
  __shared__ float sxF[16][35];
  __shared__ __align__(16) unsigned short sxA2[16 * 72];
  __shared__ float sxF2[16][35];
  __shared__ __align__(16) unsigned short hw_[4][16 * 40];
  __shared__ float yred[4][16][49];
  int t = threadIdx.x;
  int w = t >> 6, lane = t & 63, quad = lane >> 4, col = lane & 15;
  int r0 = blockIdx.x * 16;
  int nr = min(16, SS - r0);

  for (int i = t; i < 16 * 72; i += 256) { soA[i] = 0; sxA2[i] = 0; }
  for (int i = t; i < 16 * 35; i += 256) { ((float*)sxF)[i] = 0.f; ((float*)sxF2)[i] = 0.f; }
  for (int i = t; i < nr * DD; i += 256) {
    int r = i / DD, d = i - r * DD;
    int row = r0 + r;
    int ii = row / HW, jj = row - ii * HW;
    float v;
    if (d < CC) v = cell[ii * CC + d];
    else if (d < 2 * CC) v = cell[jj * CC + (d - CC)];
    else if (d == 32) v = (float)((ii / WW) - (jj / WW)) * 0.25f;
    else v = (float)((ii % WW) - (jj % WW)) * 0.25f;
    sxF[r][d] = v;
  }

  {
    int h = w >> 1, p = w & 1;
    const float* eA = eAB + ((size_t)((h * 2 + p) * 2 + 0) * 81) * 96;
    const float* eB = eAB + ((size_t)((h * 2 + p) * 2 + 1) * 81) * 96;
    int tl = lane >> 2, asub = lane & 3;
    int row = r0 + tl;
    int tc = row < SS ? row : SS - 1;
    int it = tc / HW, jt = tc - it * HW;
    const float* eAr = eA + it * 96 + asub * 24;
    const float* eBr = eB + jt * 96 + asub * 24;
    unsigned short etmp[24];
#pragma unroll
    for (int k = 0; k < 24; k++) etmp[k] = f2b(eAr[k] * eBr[k]);
    unsigned short* Eb = &sE[w][tl * 96 + asub * 24];
#pragma unroll
    for (int k = 0; k < 3; k++)
      *(bf16x8*)(Eb + k * 8) = *(bf16x8*)(etmp + k * 8);
    const unsigned short* vf = vfragL1 + (size_t)(h * 2 + p) * 32 * 96;
    f32x4 acc0 = {0.f, 0.f, 0.f, 0.f}, acc1 = {0.f, 0.f, 0.f, 0.f};
#pragma unroll
    for (int c = 0; c < 3; c++) {
      bf16x8 ea = *(const bf16x8*)&sE[w][col * 96 + c * 32 + quad * 8];
      bf16x8 vb0 = *(const bf16x8*)&vf[col * 96 + c * 32 + quad * 8];
      bf16x8 vb1 = *(const bf16x8*)&vf[(16 + col) * 96 + c * 32 + quad * 8];
      acc0 = __builtin_amdgcn_mfma_f32_16x16x32_bf16(ea, vb0, acc0, 0, 0, 0);
      acc1 = __builtin_amdgcn_mfma_f32_16x16x32_bf16(ea, vb1, acc1, 0, 0, 0);
    }
    float Sr[4];
#pragma unroll
    for (int r = 0; r < 4; r++) Sr[r] = __shfl(acc1[r], (lane & 48) + 1);
#pragma unroll
    for (int r = 0; r < 4; r++) {
      int rr = quad * 4 + r;
      float inv = 1.f / Sr[r];
      yred[w][rr][col] = acc0[r] * inv;
      if (col == 0) yred[w][rr][16] = acc1[r] * inv;
    }
  }
  __syncthreads();
  for (int i = t; i < 16 * DD; i += 256) {
    int r = i / DD, dd = i - r * DD;
    int h2 = dd / HD, d2 = dd - h2 * HD;
    soA[r * 72 + dd] = f2b(yred[2 * h2][r][d2] + yred[2 * h2 + 1][r][d2]);
  }
  __syncthreads();

  if (w == 0) {
    bf16x8 a0 = *(const bf16x8*)&soA[col * 72 + quad * 8];
    bf16x8 a1 = *(const bf16x8*)&soA[col * 72 + 32 + quad * 8];
    f32x4 y[3];
#pragma unroll
    for (int nt = 0; nt < 3; nt++) {
      int n = nt * 16 + col;
      bf16x8 b0 = *(const bf16x8*)&opwp[n * 64 + quad * 8];
      bf16x8 b1 = *(const bf16x8*)&opwp[n * 64 + 32 + quad * 8];
      f32x4 acc = {0.f, 0.f, 0.f, 0.f};
      acc = __builtin_amdgcn_mfma_f32_16x16x32_bf16(a0, b0, acc, 0, 0, 0);
      y[nt] = __builtin_amdgcn_mfma_f32_16x16x32_bf16(a1, b1, acc, 0, 0, 0);
    }
    float yv[3][4];
    float s1[4] = {0.f, 0.f, 0.f, 0.f}, s2[4] = {0.f, 0.f, 0.f, 0.f};
#pragma unroll
    for (int nt = 0; nt < 3; nt++) {
      int d = nt * 16 + col;
      bool vd = d < DD;
      float ob = vd ? opb[d] : 0.f;
#pragma unroll
      for (int r = 0; r < 4; r++) {
        int row = quad * 4 + r;
        float v = vd ? (y[nt][r] + ob + sxF[row][d]) : 0.f;
        yv[nt][r] = v;
        s1[r] += v;
        s2[r] += v * v;
      }
    }
#pragma unroll
    for (int msk = 1; msk <= 8; msk <<= 1)
#pragma unroll
      for (int r = 0; r < 4; r++) {
        s1[r] += __shfl_xor(s1[r], msk);
        s2[r] += __shfl_xor(s2[r], msk);
      }
#pragma unroll
    for (int r = 0; r < 4; r++) {
      int row = quad * 4 + r;
      float mean = s1[r] * (1.f / DD);
      float var = s2[r] * (1.f / DD) - mean * mean;
      float rs = rsqrtf(var + EPSF);
#pragma unroll
      for (int nt = 0; nt < 3; nt++) {
        int d = nt * 16 + col;
        if (d < DD) {
          float o = (yv[nt][r] - mean) * rs * g1v[d] + b1v[d];
          sxF2[row][d] = o;
          sxA2[row * 72 + d] = f2b(o);
        }
      }
    }
  }
  __syncthreads();

  bf16x8 a0 = *(const bf16x8*)&sxA2[col * 72 + quad * 8];
  bf16x8 a1 = *(const bf16x8*)&sxA2[col * 72 + 32 + quad * 8];
  unsigned short* myh = &hw_[w][0];
  f32x4 acc3[3];
#pragma unroll
  for (int nt = 0; nt < 3; nt++) acc3[nt] = (f32x4){0.f, 0.f, 0.f, 0.f};
  for (int kt = 0; kt < 16; kt++) {
    int fbase = kt * 128 + w * 32;
#pragma unroll
    for (int nt = 0; nt < 2; nt++) {
      int f = fbase + nt * 16 + col;
      bf16x8 b0f = *(const bf16x8*)&w1p[f * 64 + quad * 8];
      bf16x8 b1f = *(const bf16x8*)&w1p[f * 64 + 32 + quad * 8];
      f32x4 hacc = {0.f, 0.f, 0.f, 0.f};
      hacc = __builtin_amdgcn_mfma_f32_16x16x32_bf16(a0, b0f, hacc, 0, 0, 0);
      hacc = __builtin_amdgcn_mfma_f32_16x16x32_bf16(a1, b1f, hacc, 0, 0, 0);
      float bias = fb1[f];
#pragma unroll
      for (int r = 0; r < 4; r++) {
        float hv = fmaxf(hacc[r] + bias, 0.f);
        myh[(quad * 4 + r) * 40 + nt * 16 + col] = f2b(hv);
      }
    }
    bf16x8 pa = *(const bf16x8*)&myh[col * 40 + quad * 8];
#pragma unroll
    for (int nt = 0; nt < 3; nt++) {
      int n = nt * 16 + col;
      bf16x8 wb = *(const bf16x8*)&w2p[(size_t)n * FF + fbase + quad * 8];
      acc3[nt] = __builtin_amdgcn_mfma_f32_16x16x32_bf16(pa, wb, acc3[nt], 0, 0, 0);
    }
  }
#pragma unroll
  for (int nt = 0; nt < 3; nt++)
#pragma unroll
    for (int r = 0; r < 4; r++)
      yred[w][quad * 4 + r][nt * 16 + col] = acc3[nt][r];
  __syncthreads();
  if (w == 0) {
    float yv[3][4];
    float s1[4] = {0.f, 0.f, 0.f, 0.f}, s2[4] = {0.f, 0.f, 0.f, 0.f};
#pragma unroll
    for (int nt = 0; nt < 3; nt++) {
      int d = nt * 16 + col;
      bool valid = d < DD;
      float b2x = valid ? fb2[d] : 0.f;
#pragma unroll
      for (int r = 0; r < 4; r++) {
        int row = quad * 4 + r;
        float v = yred[0][row][nt * 16 + col] + yred[1][row][nt * 16 + col]
                + yred[2][row][nt * 16 + col] + yred[3][row][nt * 16 + col];
        v = valid ? (v + b2x + sxF2[row][d]) : 0.f;
        yv[nt][r] = v;
        s1[r] += v;
        s2[r] += v * v;
      }
    }
#pragma unroll
    for (int msk = 1; msk <= 8; msk <<= 1)
#pragma unroll
      for (int r = 0; r < 4; r++) {
        s1[r] += __shfl_xor(s1[r], msk);
        s2[r] += __shfl_xor(s2[r], msk);
      }
#pragma unroll
    for (int r = 0; r < 4; r++) {
      int row = quad * 4 + r;
      if (row >= nr) continue;
      float mean = s1[r] * (1.f / DD);
      float var = s2[r] * (1.f / DD) - mean * mean;
      float rs = rsqrtf(var + EPSF);
#pragma unroll
      for (int nt = 0; nt < 3; nt++) {
        int d = nt * 16 + col;
        if (d < DD)
          x[(size_t)(r0 + row) * DD + d] = (yv[nt][r] - mean) * rs * g2v[d] + b2v[d];
      }
    }
  }
}

// ---- dispatch 5: layer-2 qkv, 16 rows/block (R13 structure) ----
__global__ __launch_bounds__(256) void qkv2_kernel(
    const float* __restrict__ x, const unsigned short* __restrict__ ipwp,
    const float* __restrict__ ipb, const int* __restrict__ abase,
    float* __restrict__ qkv, unsigned short* __restrict__ kfp,
    unsigned short* __restrict__ vfp, float* __restrict__ v16) {
  __shared__ __align__(16) unsigned short sxA[16 * 72];
  int t = threadIdx.x;
  int w = t >> 6, lane = t & 63, quad = lane >> 4, col = lane & 15;
  bool qpart = blockIdx.x >= 411;
  int row0 = qpart ? (abase[0] * HW + (blockIdx.x - 411) * 16) : blockIdx.x * 16;
  int nr = min(16, SS - row0);
  for (int i = t; i < 16 * 72; i += 256) sxA[i] = 0;
  __syncthreads();
  for (int i = t; i < nr * DD; i += 256) {
    int r = i / DD, d = i - r * DD;
    sxA[r * 72 + d] = f2b(x[(size_t)(row0 + r) * DD + d]);
  }
  __syncthreads();
  bf16x8 a0 = *(const bf16x8*)&sxA[col * 72 + quad * 8];
  bf16x8 a1 = *(const bf16x8*)&sxA[col * 72 + 32 + quad * 8];
  if (!qpart) {
    int npass = (w == 0) ? 2 : 1;
    for (int pass = 0; pass < npass; pass++) {
      int nt = (pass == 0) ? w : 4;
      int n = DD + nt * 16 + col;
      int nc = n < 112 ? n : 111;
      bf16x8 b0 = *(const bf16x8*)&ipwp[nc * 64 + quad * 8];
      bf16x8 b1 = *(const bf16x8*)&ipwp[nc * 64 + 32 + quad * 8];
      f32x4 acc = {0.f, 0.f, 0.f, 0.f};
      acc = __builtin_amdgcn_mfma_f32_16x16x32_bf16(a0, b0, acc, 0, 0, 0);
      acc = __builtin_amdgcn_mfma_f32_16x16x32_bf16(a1, b1, acc, 0, 0, 0);
      if (n < 102) {
        float bias = ipb[n];
        int kd = n - DD;
#pragma unroll
        for (int r = 0; r < 4; r++) {
          int m = quad * 4 + r;
          if (m >= nr) continue;
          int tok = row0 + m;
          float val = acc[r] + bias;
          int T = tok >> 7, tl = tok & 127;
          if (kd < 2 * HD) {
            int h = kd >= HD;
            int d = kd - h * HD;
            int colf = tl >> 3, ntk = tl & 7;
            kfp[(((size_t)h * NTILES + T) * 8 + ntk) * 512 +
                ((d >> 3) * 16 + colf) * 8 + (d & 7)] = f2b(val);
          } else {
            int vd = kd - 2 * HD;
            int h = vd >= HD;
            int d = vd - h * HD;
            if (d < 16) {
              int c = tl >> 5, qf = (tl >> 3) & 3, j = tl & 7;
              vfp[(((size_t)h * NTILES + T) * 4 + c) * 512 +
                  (qf * 16 + d) * 8 + j] = f2b(val);
            } else {
              v16[(size_t)h * (NTILES * 128) + tok] = val;
            }
          }
        }
      }
    }
  } else {
    if (w < 3) {
      int n = w * 16 + col;
      bf16x8 b0 = *(const bf16x8*)&ipwp[n * 64 + quad * 8];
      bf16x8 b1 = *(const bf16x8*)&ipwp[n * 64 + 32 + quad * 8];
      f32x4 acc = {0.f, 0.f, 0.f, 0.f};
      acc = __builtin_amdgcn_mfma_f32_16x16x32_bf16(a0, b0, acc, 0, 0, 0);
      acc = __builtin_amdgcn_mfma_f32_16x16x32_bf16(a1, b1, acc, 0, 0, 0);
      if (n < DD) {
        float bias = ipb[n];
#pragma unroll
        for (int r = 0; r < 4; r++) {
          int m = row0 + quad * 4 + r;
          if (m < SS) qkv[(size_t)m * 102 + n] = acc[r] + bias;
        }
      }
    }
  }
}

// ---- dispatch 6: layer-2 attention, ONE tile per block, atomic accumulation ----
// grid (2, NHEAD, NTILES) = 208 blocks. Fixed-max exp => partials are plain sums;
// device-scope fp32 atomicAdd into o_sum[q*DD + h*HD + d] / l_sum[h*128 + q].
__global__ __launch_bounds__(256) void attn2_kernel(
    const float* __restrict__ qkv, const unsigned short* __restrict__ kfp,
    const unsigned short* __restrict__ vfp, const float* __restrict__ v16,
    const int* __restrict__ abase, float* __restrict__ o_sum, float* __restrict__ l_sum) {
  __shared__ __align__(16) unsigned short scb[4][16 * 136];
  int t = threadIdx.x, w = t >> 6, lane = t & 63, quad = lane >> 4, col = lane & 15;
  int h = blockIdx.y;
  int tile = blockIdx.z;
  int base = abase[0] * HW;
  int q0 = blockIdx.x * QB;
  const float scale = 0.24253562503633297f;
  const unsigned short* kf = kfp + (size_t)h * (NTILES * 8 * 512);
  const unsigned short* vf = vfp + (size_t)h * (NTILES * 4 * 512);
  const float* v16h = v16 + (size_t)h * (NTILES * 128);
  unsigned short* myscb = &scb[w][0];

  int mq = base + q0 + w * 16 + col;
  int qc = mq < SS ? mq : SS - 1;
  bf16x8 aq;
#pragma unroll
  for (int j = 0; j < 8; j++) {
    int d = quad * 8 + j;
    aq[j] = (short)((d < HD) ? f2b(qkv[(size_t)qc * 102 + h * HD + d] * scale) : 0);
  }

  int k0 = tile * 128;
  const unsigned short* kt = kf + (size_t)tile * (8 * 512);
  f32x4 s[8];
#pragma unroll
  for (int nt = 0; nt < 8; nt++) {
    bf16x8 kb = *(const bf16x8*)(kt + nt * 512 + lane * 8);
    f32x4 z = {0.f, 0.f, 0.f, 0.f};
    s[nt] = __builtin_amdgcn_mfma_f32_16x16x32_bf16(aq, kb, z, 0, 0, 0);
  }
  if (k0 + 128 > SS) {
#pragma unroll
    for (int nt = 0; nt < 8; nt++)
      if (k0 + col * 8 + nt >= SS) {
        s[nt][0] = -1e30f; s[nt][1] = -1e30f; s[nt][2] = -1e30f; s[nt][3] = -1e30f;
      }
  }
  float lreg[4];
#pragma unroll
  for (int r = 0; r < 4; r++) {
    bf16x8 pv;
    float psl = 0.f;
#pragma unroll
    for (int nt = 0; nt < 8; nt++) {
      float p = __expf(fminf(s[nt][r], 70.f));
      s[nt][r] = p;
      psl += p;
      pv[nt] = (short)f2b(p);
    }
    lreg[r] = psl;
    *(bf16x8*)(myscb + (quad * 4 + r) * 136 + col * 8) = pv;
  }
  float o16a[4];
  f32x4 va = *(const f32x4*)(v16h + k0 + col * 8);
  f32x4 vb4 = *(const f32x4*)(v16h + k0 + col * 8 + 4);
#pragma unroll
  for (int r = 0; r < 4; r++) {
    o16a[r] = s[0][r] * va[0] + s[1][r] * va[1] + s[2][r] * va[2] + s[3][r] * va[3]
            + s[4][r] * vb4[0] + s[5][r] * vb4[1] + s[6][r] * vb4[2] + s[7][r] * vb4[3];
  }
  f32x4 oacc = {0.f, 0.f, 0.f, 0.f};
  const unsigned short* vt = vf + (size_t)tile * (4 * 512);
#pragma unroll
  for (int c = 0; c < 4; c++) {
    bf16x8 pa = *(const bf16x8*)(myscb + col * 136 + c * 32 + quad * 8);
    bf16x8 vbf = *(const bf16x8*)(vt + c * 512 + lane * 8);
    oacc = __builtin_amdgcn_mfma_f32_16x16x32_bf16(pa, vbf, oacc, 0, 0, 0);
  }
#pragma unroll
  for (int msk = 1; msk <= 8; msk <<= 1)
#pragma unroll
    for (int r = 0; r < 4; r++) {
      o16a[r] += __shfl_xor(o16a[r], msk);
      lreg[r] += __shfl_xor(lreg[r], msk);
    }
#pragma unroll
  for (int r = 0; r < 4; r++) {
    int ql = q0 + w * 16 + quad * 4 + r;
    if (ql < HW) {
      atomicAdd(&o_sum[(size_t)ql * DD + h * HD + col], oacc[r]);
      if (col == 0) {
        atomicAdd(&o_sum[(size_t)ql * DD + h * HD + 16], o16a[r]);
        atomicAdd(&l_sum[h * 128 + ql], lreg[r]);
      }
    }
  }
}

// ---- dispatch 7: fl2a: read summed O/l + proj + LN1 + 1-kt partial FF ----
// grid (6 rowgroups, KSPLIT=16).
__global__ __launch_bounds__(256) void fl2a_kernel(
    const float* __restrict__ o_sum, const float* __restrict__ l_sum,
    const unsigned short* __restrict__ opwp, const float* __restrict__ opb,
    const float* __restrict__ g1v, const float* __restrict__ b1v,
    const unsigned short* __restrict__ w1p, const unsigned short* __restrict__ w2p,
    const float* __restrict__ fb1, const int* __restrict__ abase,
    const float* __restrict__ x, float* __restrict__ xln, float* __restrict__ ypart) {
  __shared__ __align__(16) unsigned short soA[16 * 72];
  __shared__ float sxF[16][35];
  __shared__ __align__(16) unsigned short sxA2[16 * 72];
  __shared__ __align__(16) unsigned short hw_[4][16 * 40];
  __shared__ float yred[4][16][49];
  int t = threadIdx.x;
  int w = t >> 6, lane = t & 63, quad = lane >> 4, col = lane & 15;
  int sp = blockIdx.y;
  int base = abase[0] * HW;
  int ql0 = blockIdx.x * 16;
  int nr = min(16, HW - ql0);
  int r0 = base + ql0;

  for (int i = t; i < 16 * 72; i += 256) { soA[i] = 0; sxA2[i] = 0; }
  for (int i = t; i < 16 * 35; i += 256) ((float*)sxF)[i] = 0.f;
  __syncthreads();
  for (int i = t; i < nr * DD; i += 256) {
    int r = i / DD, rem = i - r * DD;
    sxF[r][rem] = x[(size_t)(r0 + r) * DD + rem];
    int ql = ql0 + r;
    int h = rem / HD;
    float L = l_sum[h * 128 + ql];
    float O = o_sum[(size_t)ql * DD + rem];
    soA[r * 72 + rem] = f2b(O / L);
  }
  __syncthreads();
  if (w == 0) {
    bf16x8 a0 = *(const bf16x8*)&soA[col * 72 + quad * 8];
    bf16x8 a1 = *(const bf16x8*)&soA[col * 72 + 32 + quad * 8];
    f32x4 y[3];
#pragma unroll
    for (int nt = 0; nt < 3; nt++) {
      int n = nt * 16 + col;
      bf16x8 b0 = *(const bf16x8*)&opwp[n * 64 + quad * 8];
      bf16x8 b1 = *(const bf16x8*)&opwp[n * 64 + 32 + quad * 8];
      f32x4 acc = {0.f, 0.f, 0.f, 0.f};
      acc = __builtin_amdgcn_mfma_f32_16x16x32_bf16(a0, b0, acc, 0, 0, 0);
      y[nt] = __builtin_amdgcn_mfma_f32_16x16x32_bf16(a1, b1, acc, 0, 0, 0);
    }
    float yv[3][4];
    float s1[4] = {0.f, 0.f, 0.f, 0.f}, s2[4] = {0.f, 0.f, 0.f, 0.f};
#pragma unroll
    for (int nt = 0; nt < 3; nt++) {
      int d = nt * 16 + col;
      bool vd = d < DD;
      float ob = vd ? opb[d] : 0.f;
#pragma unroll
      for (int r = 0; r < 4; r++) {
        int row = quad * 4 + r;
        float v = vd ? (y[nt][r] + ob + sxF[row][d]) : 0.f;
        yv[nt][r] = v;
        s1[r] += v;
        s2[r] += v * v;
      }
    }
#pragma unroll
    for (int msk = 1; msk <= 8; msk <<= 1)
#pragma unroll
      for (int r = 0; r < 4; r++) {
        s1[r] += __shfl_xor(s1[r], msk);
        s2[r] += __shfl_xor(s2[r], msk);
      }
#pragma unroll
    for (int r = 0; r < 4; r++) {
      int row = quad * 4 + r;
      float mean = s1[r] * (1.f / DD);
      float var = s2[r] * (1.f / DD) - mean * mean;
      float rs = rsqrtf(var + EPSF);
#pragma unroll
      for (int nt = 0; nt < 3; nt++) {
        int d = nt * 16 + col;
        if (d < DD) {
          float o = (yv[nt][r] - mean) * rs * g1v[d] + b1v[d];
          sxA2[row * 72 + d] = f2b(o);
          if (sp == 0 && row < nr)
            xln[(size_t)(ql0 + row) * DD + d] = o;
        }
      }
    }
  }
  __syncthreads();
  // partial FF: 1 kt tile (kt = sp)
  bf16x8 a0 = *(const bf16x8*)&sxA2[col * 72 + quad * 8];
  bf16x8 a1 = *(const bf16x8*)&sxA2[col * 72 + 32 + quad * 8];
  unsigned short* myh = &hw_[w][0];
  f32x4 acc3[3];
#pragma unroll
  for (int nt = 0; nt < 3; nt++) acc3[nt] = (f32x4){0.f, 0.f, 0.f, 0.f};
  {
    int fbase = sp * 128 + w * 32;
#pragma unroll
    for (int nt = 0; nt < 2; nt++) {
      int f = fbase + nt * 16 + col;
      bf16x8 b0f = *(const bf16x8*)&w1p[f * 64 + quad * 8];
      bf16x8 b1f = *(const bf16x8*)&w1p[f * 64 + 32 + quad * 8];
      f32x4 hacc = {0.f, 0.f, 0.f, 0.f};
      hacc = __builtin_amdgcn_mfma_f32_16x16x32_bf16(a0, b0f, hacc, 0, 0, 0);
      hacc = __builtin_amdgcn_mfma_f32_16x16x32_bf16(a1, b1f, hacc, 0, 0, 0);
      float bias = fb1[f];
#pragma unroll
      for (int r = 0; r < 4; r++) {
        float hv = fmaxf(hacc[r] + bias, 0.f);
        myh[(quad * 4 + r) * 40 + nt * 16 + col] = f2b(hv);
      }
    }
    bf16x8 pa = *(const bf16x8*)&myh[col * 40 + quad * 8];
#pragma unroll
    for (int nt = 0; nt < 3; nt++) {
      int n = nt * 16 + col;
      bf16x8 wb = *(const bf16x8*)&w2p[(size_t)n * FF + fbase + quad * 8];
      acc3[nt] = __builtin_amdgcn_mfma_f32_16x16x32_bf16(pa, wb, acc3[nt], 0, 0, 0);
    }
  }
#pragma unroll
  for (int nt = 0; nt < 3; nt++)
#pragma unroll
    for (int r = 0; r < 4; r++)
      yred[w][quad * 4 + r][nt * 16 + col] = acc3[nt][r];
  __syncthreads();
  if (w == 0) {
    for (int i = lane; i < nr * DD; i += 64) {
      int r = i / DD, d = i - r * DD;
      float v = yred[0][r][d] + yred[1][r][d] + yred[2][r][d] + yred[3][r][d];
      ypart[((size_t)sp * HW + ql0 + r) * DD + d] = v;
    }
  }
}

// ---- dispatch 8: fl2b: reduce 16 ksplits + bias + residual + LN2 -> x ----
__global__ __launch_bounds__(256) void fl2b_kernel(
    const float* __restrict__ ypart, const float* __restrict__ xln,
    const float* __restrict__ fb2, const float* __restrict__ g2v,
    const float* __restrict__ b2v, const int* __restrict__ abase,
    float* __restrict__ x) {
  int t = threadIdx.x;
  int row = blockIdx.x * 32 + (t >> 3);
  int s8 = t & 7;
  if (row >= HW) return;
  int base = abase[0] * HW;
  float yv[5];
  float s1 = 0.f, s2 = 0.f;
  int cnt = 0;
  for (int d = s8; d < DD; d += 8) {
    float v = fb2[d] + xln[(size_t)row * DD + d];
#pragma unroll
    for (int sp = 0; sp < KSPLIT; sp++)
      v += ypart[((size_t)sp * HW + row) * DD + d];
    yv[cnt++] = v;
    s1 += v;
    s2 += v * v;
  }
  s1 += __shfl_xor(s1, 1); s2 += __shfl_xor(s2, 1);
  s1 += __shfl_xor(s1, 2); s2 += __shfl_xor(s2, 2);
  s1 += __shfl_xor(s1, 4); s2 += __shfl_xor(s2, 4);
  float mean = s1 * (1.f / DD);
  float var = s2 * (1.f / DD) - mean * mean;
  float rs = rsqrtf(var + EPSF);
  cnt = 0;
  for (int d = s8; d < DD; d += 8)
    x[(size_t)(base + row) * DD + d] = (yv[cnt++] - mean) * rs * g2v[d] + b2v[d];
}

// ---- dispatch 9: final ----
__global__ __launch_bounds__(64) void final_kernel(
    const float* __restrict__ x, const int* __restrict__ aidx, float* __restrict__ out) {
  int d = threadIdx.x;
  if (d >= DD) return;
  int start = (*aidx) * HW;
  float acc = 0.f;
  for (int j = 0; j < HW; j++) acc += x[(size_t)(start + j) * DD + d];
  out[d] = acc * (1.f / HW);
}

extern "C" void kernel_launch(void* const* d_in, const int* in_sizes, int n_in,
                              void* d_out, int out_size, void* d_ws, size_t ws_size,
                              hipStream_t stream) {
  const float* obs = (const float*)d_in[0];
  const float* c1w = (const float*)d_in[1];
  const float* c1b = (const float*)d_in[2];
  const float* c2w = (const float*)d_in[3];
  const float* c2b = (const float*)d_in[4];
  const float* ipw = (const float*)d_in[5];
  const float* ipb = (const float*)d_in[6];
  const float* opw = (const float*)d_in[7];
  const float* opb = (const float*)d_in[8];
  const float* l1w = (const float*)d_in[9];
  const float* l1b = (const float*)d_in[10];
  const float* l2w = (const float*)d_in[11];
  const float* l2b = (const float*)d_in[12];
  const float* g1 = (const float*)d_in[13];
  const float* b1 = (const float*)d_in[14];
  const float* g2 = (const float*)d_in[15];
  const float* b2 = (const float*)d_in[16];
  float* out = (float*)d_out;

  float* ws = (float*)d_ws;
  size_t off = 0;
  float* x     = ws + off; off += SS * DD;
  float* qkv   = ws + off; off += SS * 102;
  float* cell  = ws + off; off += HW * CC;
  int*   aidx  = (int*)(ws + off); off += 1;
  off = (off + 3) & ~(size_t)3;
  float* Pt    = ws + off; off += 2 * HW * 102;
  float* eAB   = ws + off; off += NEAB;
  float* xln   = ws + off; off += HW * DD;
  float* ypart = ws + off; off += (size_t)KSPLIT * HW * DD;
  off = (off + 3) & ~(size_t)3;
  unsigned short* vfragL1 = (unsigned short*)(ws + off); off += NVFL1 / 2;
  unsigned short* kfp  = (unsigned short*)(ws + off); off += NKF / 2;
  unsigned short* vfp  = (unsigned short*)(ws + off); off += NVF / 2;
  float* v16 = ws + off; off += NV16;
  float* o_sum = ws + off; off += 128 * DD;   // 4352
  float* l_sum = ws + off; off += 256;        // contiguous with o_sum (zeroed together)
  unsigned short* ipwp = (unsigned short*)(ws + off); off += 2 * NIP / 2;
  unsigned short* opwp = (unsigned short*)(ws + off); off += 2 * NOP / 2;
  unsigned short* w1p  = (unsigned short*)(ws + off); off += 2 * NW1 / 2;
  unsigned short* w2p  = (unsigned short*)(ws + off); off += 2 * NW2 / 2;

  const int prep_grid = 1 + LPREP_BLOCKS + ZERO_BLOCKS;
  const int pt_blocks = (2 * HW * 102 + 255) / 256;
  const int exp_blocks = (NEAB + NVFL1 + 255) / 256;
  const int fl1_blocks = (SS + 15) / 16;   // 411

  prep_kernel<<<prep_grid, 256, 0, stream>>>(
      obs, c1w, c1b, c2w, c2b, cell, aidx,
      ipw, opw, l1w, l2w, ipwp, opwp, w1p, w2p, kfp, vfp, v16, o_sum);
  ptprep_kernel<<<pt_blocks, 256, 0, stream>>>(cell, ipw, ipb, Pt);
  expprep_kernel<<<exp_blocks, 256, 0, stream>>>(Pt, eAB, vfragL1);
  fl1_kernel<<<fl1_blocks, 256, 0, stream>>>(
      cell, eAB, vfragL1, opwp, opb, g1, b1, w1p, w2p, l1b, l2b, g2, b2, x);
  qkv2_kernel<<<419, 256, 0, stream>>>(
      x, ipwp + NIP, ipb + 102, aidx, qkv, kfp, vfp, v16);
  dim3 a2g(2, NHEAD, NTILES);
  attn2_kernel<<<a2g, 256, 0, stream>>>(qkv, kfp, vfp, v16, aidx, o_sum, l_sum);
  dim3 f2g(6, KSPLIT);
  fl2a_kernel<<<f2g, 256, 0, stream>>>(
      o_sum, l_sum, opwp + NOP, opb + DD, g1 + DD, b1 + DD,
      w1p + NW1, w2p + NW2, l1b + FF, aidx, x, xln, ypart);
  fl2b_kernel<<<3, 256, 0, stream>>>(
      ypart, xln, l2b + DD, g2 + DD, b2 + DD, aidx, x);
  final_kernel<<<1, 64, 0, stream>>>(x, aidx, out);
}